// Round 11
// baseline (129.471 us; speedup 1.0000x reference)
//
#include <hip/hip_runtime.h>
#include <math.h>

namespace {

constexpr int Cc  = 512;
constexpr int HW  = 196;
constexpr int HWP = 224;
constexpr int OC  = 2048;
constexpr float TEMP   = 0.35355339059327373f;  // 1/sqrt(KEY_DIM)
constexpr float INV196 = 1.0f / 196.0f;

typedef __attribute__((ext_vector_type(8))) _Float16 half8;
typedef __attribute__((ext_vector_type(4))) float f32x4;

__device__ __forceinline__ void gload_lds16(const void* g, void* l) {
  __builtin_amdgcn_global_load_lds(
      (const __attribute__((address_space(1))) void*)g,
      (__attribute__((address_space(3))) void*)l, 16, 0, 0);
}

#define MFMAH(a, b, c) __builtin_amdgcn_mfma_f32_16x16x32_f16((a), (b), (c), 0, 0, 0)

// ================= K1: wv_prep (512 blocks) || pool (4096 blocks, XCD-affine) =================
__global__ __launch_bounds__(256) void fat_prep(
    const float* __restrict__ x, const float* __restrict__ Wv,
    _Float16* __restrict__ WvA, float* __restrict__ WvT,
    _Float16* __restrict__ xpH, _Float16* __restrict__ xpL,
    float* __restrict__ xm) {
  __shared__ char sm1[8448];
  int bid = blockIdx.x;
  int t = threadIdx.x;
  if (bid < 512) {
    // ---- wv_prep: WvA fragments + WvT transpose ----
    float* tile = (float*)sm1;          // [64][33]
    int kk = bid >> 5;
    int rq = bid & 31;
    int w = t >> 6, lane = t & 63;
    int r = rq * 4 + w;
    int oc = r * 16 + (lane & 15);
    int c0 = kk * 32 + (lane >> 4) * 8;
    const float* src = Wv + (size_t)oc * 512 + c0;
    float4 v0 = *(const float4*)src;
    float4 v1 = *(const float4*)(src + 4);
    float vals[8] = {v0.x, v0.y, v0.z, v0.w, v1.x, v1.y, v1.z, v1.w};
    half8 hi, lo;
    #pragma unroll
    for (int e = 0; e < 8; ++e) {
      _Float16 h = (_Float16)vals[e];
      hi[e] = h;
      lo[e] = (_Float16)(vals[e] - (float)h);
    }
    *(half8*)(WvA + ((size_t)(kk * 2 + 0) * 128 + r) * 512 + lane * 8) = hi;
    *(half8*)(WvA + ((size_t)(kk * 2 + 1) * 128 + r) * 512 + lane * 8) = lo;
    int ocl = w * 16 + (lane & 15);
    int cl = (lane >> 4) * 8;
    #pragma unroll
    for (int e = 0; e < 8; ++e) tile[ocl * 33 + cl + e] = vals[e];
    __syncthreads();
    int ocb = rq * 64;
    #pragma unroll
    for (int k2 = 0; k2 < 8; ++k2) {
      int idx = k2 * 256 + t;
      int c_l = idx >> 6, oc_l = idx & 63;
      WvT[(size_t)(kk * 32 + c_l) * 2048 + ocb + oc_l] = tile[oc_l * 33 + c_l];
    }
  } else {
    // ---- pool: avgpool3x3 + spatial mean -> f16 hi/lo xp [nd][hw][c] ----
    float* tl = (float*)sm1;            // [8][264]
    int pb = bid - 512;
    int nd = (((pb >> 9) & 7) << 3) | (pb & 7);   // XCD-affine
    int cg = (pb >> 3) & 63;
    int n = nd >> 5, d = nd & 31;
    int c0 = cg * 8;
    int cl = t >> 5, s = t & 31;
    const float* xr = x + (((size_t)(n * 512 + c0 + cl)) * 32 + d) * 256;
    float4 va = *(const float4*)(xr + s * 8);
    float4 vb = *(const float4*)(xr + s * 8 + 4);
    *(float4*)&tl[cl * 264 + s * 8] = va;
    *(float4*)&tl[cl * 264 + s * 8 + 4] = vb;
    float rs = va.x + va.y + va.z + va.w + vb.x + vb.y + vb.z + vb.w;
    #pragma unroll
    for (int off = 16; off; off >>= 1) rs += __shfl_xor(rs, off, 32);
    if (s == 0) xm[nd * 512 + c0 + cl] = rs * (1.0f / 256.0f);
    __syncthreads();
    if (t < HWP) {
      int hw = t;
      half8 hi, lo;
      if (hw < HW) {
        int y = hw / 14, xx = hw - y * 14;
        #pragma unroll
        for (int c = 0; c < 8; ++c) {
          const float* q = &tl[c * 264 + y * 16 + xx];
          float val = (q[0] + q[1] + q[2] + q[16] + q[17] + q[18] +
                       q[32] + q[33] + q[34]) * (1.0f / 9.0f);
          _Float16 h = (_Float16)val;
          hi[c] = h;
          lo[c] = (_Float16)(val - (float)h);
        }
      } else {
        #pragma unroll
        for (int c = 0; c < 8; ++c) { hi[c] = (_Float16)0.f; lo[c] = (_Float16)0.f; }
      }
      size_t off = ((size_t)nd * HWP + hw) * 512 + c0;
      *(half8*)(xpH + off) = hi;
      *(half8*)(xpL + off) = lo;
    }
  }
}

// ========== K2: attn (blocks 0..63, one per nd) || moments (64..1087) ==========
// launch_bounds (256, 2): VGPR cap 128 — moments needs ~108 (r8's (256,4) 64-cap spilled).
__global__ __launch_bounds__(256, 2) void fat_main(
    const _Float16* __restrict__ WvA, const _Float16* __restrict__ xpH,
    const _Float16* __restrict__ xpL,
    const float* __restrict__ Wq, const float* __restrict__ Wk,
    const float* __restrict__ xm,
    float* __restrict__ attn_out, float* __restrict__ sb,
    float* __restrict__ S1, float* __restrict__ S2) {
  __shared__ char smem[36864];
  int bid = blockIdx.x;
  int t = threadIdx.x;
  int w = t >> 6, lane = t & 63;

  if (bid < 64) {
    // ------------- attention path: q(4o) -> qw(4o) -> dots(coalesced) -> softmax -> s -------------
    float* xs     = (float*)smem;             // [512]           (dead after qw)
    float* qsA    = (float*)(smem + 2048);    // [32]            (dead after qw)
    float* qw     = (float*)(smem + 2176);    // [4][512]        (dead after dots)
    float* dot_l  = (float*)(smem + 10368);   // [4][256]        (dead after softmax)
    float* attn_l = (float*)(smem + 33280);   // [4][224]        (live through s)
    float* sred   = (float*)smem;             // [16][512] s-phase overlay of [0,32768)
    int nd = bid;
    int n = nd >> 5, d = nd & 31;
    xs[t] = xm[nd * 512 + t];
    xs[t + 256] = xm[nd * 512 + t + 256];
    __syncthreads();
    // q[k] for all 32 (o,kd)
    {
      int k = t >> 3, j = t & 7;
      float p = 0.f;
      #pragma unroll 8
      for (int c = j; c < 512; c += 8) p = fmaf(Wq[k * 512 + c], xs[c], p);
      p += __shfl_xor(p, 4, 8);
      p += __shfl_xor(p, 2, 8);
      p += __shfl_xor(p, 1, 8);
      if (j == 0) qsA[k] = p;
    }
    __syncthreads();
    // qw[o][c] = sum_kd q[o,kd] * Wk[o*8+kd][c]
    {
      int o = t >> 6;
      int c0 = (t & 63) * 8;
      float q[8];
      #pragma unroll
      for (int kd = 0; kd < 8; ++kd) q[kd] = qsA[o * 8 + kd];
      #pragma unroll
      for (int e = 0; e < 8; ++e) {
        float a = 0.f;
        #pragma unroll
        for (int kd = 0; kd < 8; ++kd)
          a = fmaf(q[kd], Wk[(size_t)(o * 8 + kd) * 512 + c0 + e], a);
        qw[o * 512 + c0 + e] = a;
      }
    }
    // pad dot_l entries 224..255 (read by softmax)
    if (t < 128) {
      int o = t >> 5;
      dot_l[o * 256 + 224 + (t & 31)] = -3.0e38f;
    }
    __syncthreads();
    // hoist this lane's fixed qw slice (c = lane*8 .. +8, all 4 heads) into registers
    float qwr[4][8];
    #pragma unroll
    for (int o = 0; o < 4; ++o) {
      float4 a = *(float4*)&qw[o * 512 + lane * 8];
      float4 b = *(float4*)&qw[o * 512 + lane * 8 + 4];
      qwr[o][0] = a.x; qwr[o][1] = a.y; qwr[o][2] = a.z; qwr[o][3] = a.w;
      qwr[o][4] = b.x; qwr[o][5] = b.y; qwr[o][6] = b.z; qwr[o][7] = b.w;
    }
    // dots: wave per pixel — 64 lanes read one xp row coalesced (2 x 1KB), packed reduce
    for (int i = 0; i < 56; ++i) {
      int hw = w * 56 + i;
      if (hw < HW) {
        half8 h = *(const half8*)(xpH + ((size_t)nd * HWP + hw) * 512 + lane * 8);
        half8 l = *(const half8*)(xpL + ((size_t)nd * HWP + hw) * 512 + lane * 8);
        float d0 = 0.f, d1 = 0.f, d2 = 0.f, d3 = 0.f;
        #pragma unroll
        for (int e = 0; e < 8; ++e) {
          float xv = (float)h[e] + (float)l[e];
          d0 = fmaf(qwr[0][e], xv, d0);
          d1 = fmaf(qwr[1][e], xv, d1);
          d2 = fmaf(qwr[2][e], xv, d2);
          d3 = fmaf(qwr[3][e], xv, d3);
        }
        // packed reduction: 2 butterfly levels on all 4, select by lane&3, 4 more levels
        d0 += __shfl_xor(d0, 1, 64); d1 += __shfl_xor(d1, 1, 64);
        d2 += __shfl_xor(d2, 1, 64); d3 += __shfl_xor(d3, 1, 64);
        d0 += __shfl_xor(d0, 2, 64); d1 += __shfl_xor(d1, 2, 64);
        d2 += __shfl_xor(d2, 2, 64); d3 += __shfl_xor(d3, 2, 64);
        int sel = lane & 3;
        float v = (sel == 0) ? d0 : (sel == 1) ? d1 : (sel == 2) ? d2 : d3;
        v += __shfl_xor(v, 4, 64);
        v += __shfl_xor(v, 8, 64);
        v += __shfl_xor(v, 16, 64);
        v += __shfl_xor(v, 32, 64);
        if (lane < 4) dot_l[lane * 256 + hw] = v * TEMP;   // lane o holds head o's total
      } else {
        if (lane < 4) dot_l[lane * 256 + hw] = -3.0e38f;
      }
    }
    __syncthreads();
    // softmax per head: o = t>>6, lane l handles 4 strided entries; exact division
    {
      int o = t >> 6, l = t & 63;
      float v0 = dot_l[o * 256 + l],       v1 = dot_l[o * 256 + l + 64];
      float v2 = dot_l[o * 256 + l + 128], v3 = dot_l[o * 256 + l + 192];
      float m = fmaxf(fmaxf(v0, v1), fmaxf(v2, v3));
      #pragma unroll
      for (int off = 32; off; off >>= 1) m = fmaxf(m, __shfl_xor(m, off, 64));
      float e0 = expf(v0 - m), e1 = expf(v1 - m), e2 = expf(v2 - m), e3 = expf(v3 - m);
      float s = e0 + e1 + e2 + e3;
      #pragma unroll
      for (int off = 32; off; off >>= 1) s += __shfl_xor(s, off, 64);
      float a0 = e0 / s, a1 = e1 / s, a2 = e2 / s, a3 = e3 / s;
      attn_l[o * 224 + l]       = a0;
      attn_l[o * 224 + l + 64]  = a1;
      attn_l[o * 224 + l + 128] = a2;
      if (l < 32) attn_l[o * 224 + l + 192] = a3;   // pad rows get exact 0 (e3=0)
      float* ao = attn_out + (((size_t)n * 4 + o) * 32 + d) * HW;
      ao[l] = a0;
      ao[l + 64] = a1;
      if (l + 128 < HW) ao[l + 128] = a2;
      if (l + 192 < HW) ao[l + 192] = a3;
    }
    __syncthreads();
    // s phase: wave w handles hw = w, w+4, ...; lane owns 8 channels, all 4 heads
    {
      float sa[4][8];
      #pragma unroll
      for (int o = 0; o < 4; ++o)
        #pragma unroll
        for (int e = 0; e < 8; ++e) sa[o][e] = 0.f;
      const _Float16* ph = xpH + (size_t)nd * HWP * 512 + lane * 8;
      const _Float16* pl = xpL + (size_t)nd * HWP * 512 + lane * 8;
      for (int hw = w; hw < HW; hw += 4) {
        half8 h = *(const half8*)(ph + (size_t)hw * 512);
        half8 l = *(const half8*)(pl + (size_t)hw * 512);
        float a0 = attn_l[hw], a1 = attn_l[224 + hw];
        float a2 = attn_l[448 + hw], a3 = attn_l[672 + hw];
        #pragma unroll
        for (int e = 0; e < 8; ++e) {
          float xv = (float)h[e] + (float)l[e];
          sa[0][e] = fmaf(a0, xv, sa[0][e]);
          sa[1][e] = fmaf(a1, xv, sa[1][e]);
          sa[2][e] = fmaf(a2, xv, sa[2][e]);
          sa[3][e] = fmaf(a3, xv, sa[3][e]);
        }
      }
      #pragma unroll
      for (int o = 0; o < 4; ++o) {
        float4 v0 = {sa[o][0], sa[o][1], sa[o][2], sa[o][3]};
        float4 v1 = {sa[o][4], sa[o][5], sa[o][6], sa[o][7]};
        *(float4*)&sred[(w * 4 + o) * 512 + lane * 8] = v0;
        *(float4*)&sred[(w * 4 + o) * 512 + lane * 8 + 4] = v1;
      }
    }
    __syncthreads();
    #pragma unroll
    for (int i = 0; i < 8; ++i) {
      int idx = i * 256 + t;
      int o = idx >> 9, c = idx & 511;
      sb[((size_t)nd * 4 + o) * 512 + c] =
          sred[o * 512 + c] + sred[(4 + o) * 512 + c] +
          sred[(8 + o) * 512 + c] + sred[(12 + o) * 512 + c];
    }
    return;
  }

  // ---------------- moments path (identical to r7/r9/r10) ----------------
  int b2 = bid - 64;
  int ob = (b2 >> 3) & 15;
  int nd = ((b2 >> 7) << 3) | (b2 & 7);
  int wq = w >> 1, wh = w & 1;
  int rbase = ob * 8 + wq * 4;
  int jbase = wh * 7;
  int nj = 7 - wh;
  char* ldsb = smem;
  const _Float16* xph = xpH + (size_t)nd * HWP * 512;

  f32x4 acc[4][7];
  #pragma unroll
  for (int f = 0; f < 4; ++f)
    #pragma unroll
    for (int j = 0; j < 7; ++j) acc[f][j] = (f32x4){0.f, 0.f, 0.f, 0.f};

  auto stage = [&](char* buf, int kk) {
    #pragma unroll
    for (int i = 0; i < 4; ++i) {
      if (i < 3 || t < 64) {
        int G = i * 256 + t;
        int j = G >> 6;
        int g = G & 63;              // == lane
        int hwl = g & 15, bb = g >> 4;
        const _Float16* src = xph + (size_t)(j * 16 + hwl) * 512 + kk * 32 + bb * 8;
        gload_lds16((const void*)src, (void*)(buf + G * 16));
      }
    }
  };

  stage(ldsb, 0);
  half8 ah[4], al_[4], nah[4], nal[4];
  #pragma unroll
  for (int f = 0; f < 4; ++f) {
    ah[f]  = *(const half8*)(WvA + ((size_t)0 * 128 + rbase + f) * 512 + lane * 8);
    al_[f] = *(const half8*)(WvA + ((size_t)1 * 128 + rbase + f) * 512 + lane * 8);
  }
  __syncthreads();

  int cur = 0;
  for (int kk = 0; kk < 16; ++kk) {
    if (kk < 15) {
      #pragma unroll
      for (int f = 0; f < 4; ++f) {
        nah[f] = *(const half8*)(WvA + ((size_t)((kk + 1) * 2 + 0) * 128 + rbase + f) * 512 + lane * 8);
        nal[f] = *(const half8*)(WvA + ((size_t)((kk + 1) * 2 + 1) * 128 + rbase + f) * 512 + lane * 8);
      }
      stage(ldsb + (cur ^ 1) * 13312, kk + 1);
    }
    const char* bp = ldsb + cur * 13312;
    #pragma unroll
    for (int j = 0; j < 7; ++j) {
      if (j < nj) {
        half8 bh = *(const half8*)(bp + (jbase + j) * 1024 + lane * 16);
        #pragma unroll
        for (int f = 0; f < 4; ++f) {
          acc[f][j] = MFMAH(ah[f], bh, acc[f][j]);
          acc[f][j] = MFMAH(al_[f], bh, acc[f][j]);
        }
      }
    }
    __syncthreads();
    cur ^= 1;
    #pragma unroll
    for (int f = 0; f < 4; ++f) { ah[f] = nah[f]; al_[f] = nal[f]; }
  }

  float* red = (float*)ldsb;
  float q1[4][4], q2[4][4];
  #pragma unroll
  for (int f = 0; f < 4; ++f) {
    #pragma unroll
    for (int r = 0; r < 4; ++r) {
      float u = 0.f, vsq = 0.f;
      #pragma unroll
      for (int j = 0; j < 7; ++j) {
        float v = acc[f][j][r];
        u += v;
        vsq = fmaf(v, v, vsq);
      }
      #pragma unroll
      for (int off = 8; off; off >>= 1) {
        u += __shfl_xor(u, off, 16);
        vsq += __shfl_xor(vsq, off, 16);
      }
      q1[f][r] = u; q2[f][r] = vsq;
    }
  }
  int rowq = lane >> 4;
  bool wr = (lane & 15) == 0;
  if (wh == 0 && wr) {
    #pragma unroll
    for (int f = 0; f < 4; ++f)
      #pragma unroll
      for (int r = 0; r < 4; ++r) {
        int idx = wq * 64 + f * 16 + rowq * 4 + r;
        red[idx] = q1[f][r];
        red[128 + idx] = q2[f][r];
      }
  }
  __syncthreads();
  if (wh == 1 && wr) {
    size_t base = (size_t)nd * OC + ob * 128 + wq * 64;
    #pragma unroll
    for (int f = 0; f < 4; ++f)
      #pragma unroll
      for (int r = 0; r < 4; ++r) {
        int idx = f * 16 + rowq * 4 + r;
        S1[base + idx] = red[wq * 64 + idx] + q1[f][r];
        S2[base + idx] = red[128 + wq * 64 + idx] + q2[f][r];
      }
  }
}

// ---------------- head pass 1: dotW + IN + gelu + Wout partial (64-oc x 4-nd tiles) ----------------
__global__ __launch_bounds__(256) void head_gemm(
    const float* __restrict__ WvT, const float* __restrict__ sb,
    const float* __restrict__ S1, const float* __restrict__ S2,
    const float* __restrict__ gamma, const float* __restrict__ beta,
    const float* __restrict__ Wout, float* __restrict__ pb) {
  int bid = blockIdx.x;
  int ot = bid >> 4, nt = bid & 15;
  int o = ot >> 3, ct = ot & 7;
  int cb = ct * 64;
  int ndb = nt * 4;
  int t = threadIdx.x;
  int oc_l = t & 63, g = t >> 6;
  int nd = ndb + g;
  __shared__ float ssh[4][512];
  for (int i = t; i < 2048; i += 256) {
    int ir = i >> 9, ic = i & 511;
    ssh[ir][ic] = sb[((size_t)(ndb + ir) * 4 + o) * 512 + ic];
  }
  __syncthreads();
  const float* wcol = WvT + o * 512 + cb + oc_l;
  float acc = 0.f;
  #pragma unroll 8
  for (int cp = 0; cp < 512; ++cp) {
    float wv = wcol[(size_t)cp * 2048];
    acc = fmaf(wv, ssh[g][cp], acc);
  }
  int oc = o * 512 + cb + oc_l;
  float m1 = S1[(size_t)nd * OC + oc] * INV196;
  float m2 = S2[(size_t)nd * OC + oc] * INV196;
  float var = m2 - m1 * m1;
  float rs = rsqrtf(var + 1e-5f);
  float xh = (acc - m1) * rs * gamma[oc] + beta[oc];
  float ge = 0.5f * xh * (1.0f + erff(xh * 0.70710678118654752f));
  float p = ge * Wout[oc];
  #pragma unroll
  for (int off = 32; off; off >>= 1) p += __shfl_down(p, off, 64);
  if (oc_l == 0) pb[(ct * 4 + o) * 64 + nd] = p;
}

// ---------------- head pass 2: combine 8 c-tile partials + bias ----------------
__global__ void final_out(const float* __restrict__ pb, const float* __restrict__ bout,
                          float* __restrict__ outs) {
  int t = threadIdx.x;      // 256 = o(4) x nd(64)
  int o = t >> 6, nd = t & 63;
  float s = 0.f;
  #pragma unroll
  for (int ct = 0; ct < 8; ++ct) s += pb[(ct * 4 + o) * 64 + nd];
  outs[o * 64 + nd] = s + bout[o];
}

}  // namespace

extern "C" void kernel_launch(void* const* d_in, const int* in_sizes, int n_in,
                              void* d_out, int out_size, void* d_ws, size_t ws_size,
                              hipStream_t stream) {
  const float* x     = (const float*)d_in[0];
  const float* Wq    = (const float*)d_in[1];
  const float* Wk    = (const float*)d_in[2];
  const float* Wv    = (const float*)d_in[3];
  const float* gamma = (const float*)d_in[4];
  const float* beta  = (const float*)d_in[5];
  const float* Wout  = (const float*)d_in[6];
  const float* bout  = (const float*)d_in[7];
  float* out      = (float*)d_out;
  float* attn_out = out;            // (N,4,D,196) = 50176 floats
  float* outs     = out + 50176;    // (4,N,1,D)   = 256 floats

  float* ws = (float*)d_ws;
  float*     WvT = ws;                                  // [0, 1048576)
  _Float16*  WvA = (_Float16*)(ws + 1048576);           // 2097152 f16
  _Float16*  xpH = (_Float16*)(ws + 2097152);           // 7340032 f16
  _Float16*  xpL = (_Float16*)(ws + 5767168);           // 7340032 f16
  float*     xm  = ws + 9437184;                        // 32768
  float*     S1  = ws + 9469952;                        // 131072
  float*     S2  = ws + 9601024;                        // 131072
  float*     sb  = ws + 9732096;                        // 131072
  float*     pb  = ws + 9863168;                        // 2048

  fat_prep<<<4608, 256, 0, stream>>>(x, Wv, WvA, WvT, xpH, xpL, xm);
  fat_main<<<1088, 256, 0, stream>>>(WvA, xpH, xpL, Wq, Wk, xm,
                                     attn_out, sb, S1, S2);
  head_gemm<<<512, 256, 0, stream>>>(WvT, sb, S1, S2, gamma, beta, Wout, pb);
  final_out<<<1, 256, 0, stream>>>(pb, bout, outs);
}

// Round 12
// 95.600 us; speedup vs baseline: 1.3543x; 1.3543x over previous
//
#include <hip/hip_runtime.h>
#include <math.h>

namespace {

constexpr int Cc  = 512;
constexpr int HW  = 196;
constexpr int HWP = 224;
constexpr int OC  = 2048;
constexpr float TEMP   = 0.35355339059327373f;  // 1/sqrt(KEY_DIM)
constexpr float INV196 = 1.0f / 196.0f;

typedef __attribute__((ext_vector_type(8))) _Float16 half8;
typedef __attribute__((ext_vector_type(4))) float f32x4;

__device__ __forceinline__ void gload_lds16(const void* g, void* l) {
  __builtin_amdgcn_global_load_lds(
      (const __attribute__((address_space(1))) void*)g,
      (__attribute__((address_space(3))) void*)l, 16, 0, 0);
}

#define MFMAH(a, b, c) __builtin_amdgcn_mfma_f32_16x16x32_f16((a), (b), (c), 0, 0, 0)

// ================= K1: wv_prep (512 blocks, WvA only) || pool (4096 blocks) =================
__global__ __launch_bounds__(256) void fat_prep(
    const float* __restrict__ x, const float* __restrict__ Wv,
    _Float16* __restrict__ WvA,
    _Float16* __restrict__ xpH, _Float16* __restrict__ xpL,
    float* __restrict__ xm) {
  __shared__ float tl[8][264];
  int bid = blockIdx.x;
  int t = threadIdx.x;
  if (bid < 512) {
    // ---- WvA f16 hi/lo fragments ----
    int kk = bid >> 5;
    int rq = bid & 31;
    int w = t >> 6, lane = t & 63;
    int r = rq * 4 + w;
    int oc = r * 16 + (lane & 15);
    int c0 = kk * 32 + (lane >> 4) * 8;
    const float* src = Wv + (size_t)oc * 512 + c0;
    float4 v0 = *(const float4*)src;
    float4 v1 = *(const float4*)(src + 4);
    float vals[8] = {v0.x, v0.y, v0.z, v0.w, v1.x, v1.y, v1.z, v1.w};
    half8 hi, lo;
    #pragma unroll
    for (int e = 0; e < 8; ++e) {
      _Float16 h = (_Float16)vals[e];
      hi[e] = h;
      lo[e] = (_Float16)(vals[e] - (float)h);
    }
    *(half8*)(WvA + ((size_t)(kk * 2 + 0) * 128 + r) * 512 + lane * 8) = hi;
    *(half8*)(WvA + ((size_t)(kk * 2 + 1) * 128 + r) * 512 + lane * 8) = lo;
  } else {
    // ---- pool: avgpool3x3 + spatial mean -> f16 hi/lo xp [nd][hw][c] ----
    int pb = bid - 512;
    int nd = (((pb >> 9) & 7) << 3) | (pb & 7);   // XCD-affine
    int cg = (pb >> 3) & 63;
    int n = nd >> 5, d = nd & 31;
    int c0 = cg * 8;
    int cl = t >> 5, s = t & 31;
    const float* xr = x + (((size_t)(n * 512 + c0 + cl)) * 32 + d) * 256;
    float4 va = *(const float4*)(xr + s * 8);
    float4 vb = *(const float4*)(xr + s * 8 + 4);
    *(float4*)&tl[cl][s * 8] = va;
    *(float4*)&tl[cl][s * 8 + 4] = vb;
    float rs = va.x + va.y + va.z + va.w + vb.x + vb.y + vb.z + vb.w;
    #pragma unroll
    for (int off = 16; off; off >>= 1) rs += __shfl_xor(rs, off, 32);
    if (s == 0) xm[nd * 512 + c0 + cl] = rs * (1.0f / 256.0f);
    __syncthreads();
    if (t < HWP) {
      int hw = t;
      half8 hi, lo;
      if (hw < HW) {
        int y = hw / 14, xx = hw - y * 14;
        #pragma unroll
        for (int c = 0; c < 8; ++c) {
          const float* q = &tl[c][y * 16 + xx];
          float val = (q[0] + q[1] + q[2] + q[16] + q[17] + q[18] +
                       q[32] + q[33] + q[34]) * (1.0f / 9.0f);
          _Float16 h = (_Float16)val;
          hi[c] = h;
          lo[c] = (_Float16)(val - (float)h);
        }
      } else {
        #pragma unroll
        for (int c = 0; c < 8; ++c) { hi[c] = (_Float16)0.f; lo[c] = (_Float16)0.f; }
      }
      size_t off = ((size_t)nd * HWP + hw) * 512 + c0;
      *(half8*)(xpH + off) = hi;
      *(half8*)(xpL + off) = lo;
    }
  }
}

// ---------------- attn dots: dot[nd][o][hw] = qw[o] . xp[hw]  (4 lanes per hw) ----------------
__global__ __launch_bounds__(256) void attn_dots(
    const float* __restrict__ Wq, const float* __restrict__ Wk,
    const float* __restrict__ xm,
    const _Float16* __restrict__ xpH, const _Float16* __restrict__ xpL,
    float* __restrict__ dotb) {
  int b = blockIdx.x;
  int nd = b >> 2, ch = b & 3;
  int t = threadIdx.x;
  __shared__ float xs[512];
  __shared__ float qsA[32];
  __shared__ float qw[2048];
  xs[t] = xm[nd * 512 + t];
  xs[t + 256] = xm[nd * 512 + t + 256];
  __syncthreads();
  {
    int k = t >> 3, j = t & 7;
    float p = 0.f;
    #pragma unroll 8
    for (int c = j; c < 512; c += 8) p = fmaf(Wq[k * 512 + c], xs[c], p);
    p += __shfl_xor(p, 4, 8);
    p += __shfl_xor(p, 2, 8);
    p += __shfl_xor(p, 1, 8);
    if (j == 0) qsA[k] = p;
  }
  __syncthreads();
  {
    int o = t >> 6;
    int c0 = (t & 63) * 8;
    float q[8];
    #pragma unroll
    for (int kd = 0; kd < 8; ++kd) q[kd] = qsA[o * 8 + kd];
    #pragma unroll
    for (int e = 0; e < 8; ++e) {
      float a = 0.f;
      #pragma unroll
      for (int kd = 0; kd < 8; ++kd)
        a = fmaf(q[kd], Wk[(size_t)(o * 8 + kd) * 512 + c0 + e], a);
      qw[o * 512 + c0 + e] = a;
    }
  }
  __syncthreads();
  if (t < 224) {
    int hwl = t >> 2, q = t & 3;
    int hw = ch * 56 + hwl;
    const _Float16* rh = xpH + ((size_t)nd * HWP + hw) * 512;
    const _Float16* rl = xpL + ((size_t)nd * HWP + hw) * 512;
    float d0 = 0.f, d1 = 0.f, d2 = 0.f, d3 = 0.f;
    #pragma unroll
    for (int k = 0; k < 16; ++k) {
      int cb = q * 8 + k * 32;           // interleaved c-blocks: conflict-free qw banks
      half8 h = *(const half8*)(rh + cb);
      half8 l = *(const half8*)(rl + cb);
      #pragma unroll
      for (int e = 0; e < 8; ++e) {
        float xv = (float)h[e] + (float)l[e];
        d0 = fmaf(qw[cb + e], xv, d0);
        d1 = fmaf(qw[512 + cb + e], xv, d1);
        d2 = fmaf(qw[1024 + cb + e], xv, d2);
        d3 = fmaf(qw[1536 + cb + e], xv, d3);
      }
    }
    d0 += __shfl_xor(d0, 1, 4); d0 += __shfl_xor(d0, 2, 4);
    d1 += __shfl_xor(d1, 1, 4); d1 += __shfl_xor(d1, 2, 4);
    d2 += __shfl_xor(d2, 1, 4); d2 += __shfl_xor(d2, 2, 4);
    d3 += __shfl_xor(d3, 1, 4); d3 += __shfl_xor(d3, 2, 4);
    float r = (q == 0) ? d0 : (q == 1) ? d1 : (q == 2) ? d2 : d3;
    dotb[((size_t)nd * 4 + q) * HWP + hw] = r * TEMP;
  }
}

// ---------------- softmax per (nd,o): exact division; writes attn_out + padded attn_p ----------------
__global__ void attn_soft(const float* __restrict__ dotb, float* __restrict__ attn_out,
                          float* __restrict__ attn_p) {
  int b = blockIdx.x;          // nd*4 + o
  int nd = b >> 2, o = b & 3;
  int t = threadIdx.x;
  int w = t >> 6, lane = t & 63;
  __shared__ float redm[4];
  __shared__ float reds[4];
  float v = (t < HW) ? dotb[(size_t)b * HWP + t] : -3.0e38f;
  float m = v;
  #pragma unroll
  for (int off = 32; off; off >>= 1) m = fmaxf(m, __shfl_xor(m, off, 64));
  if (lane == 0) redm[w] = m;
  __syncthreads();
  float bm = fmaxf(fmaxf(redm[0], redm[1]), fmaxf(redm[2], redm[3]));
  float e = (t < HW) ? expf(v - bm) : 0.f;
  float s = e;
  #pragma unroll
  for (int off = 32; off; off >>= 1) s += __shfl_xor(s, off, 64);
  if (lane == 0) reds[w] = s;
  __syncthreads();
  float bs = reds[0] + reds[1] + reds[2] + reds[3];
  float a = (t < HW) ? (e / bs) : 0.f;
  if (t < HW) {
    int n = nd >> 5, d = nd & 31;
    attn_out[(((size_t)n * 4 + o) * 32 + d) * HW + t] = a;
  }
  if (t < HWP) attn_p[(size_t)b * HWP + t] = a;   // zero on pad rows
}

// ---------------- moments + attention-weighted sum via 2-product f16 MFMA ----------------
// grid 1024: nd-XCD-affine; block tile 128 oc x 208 hw (one o per block: o = ob>>2).
// Epilogue: S1 = sum_hw v, S2 = sum_hw v^2, S3 = sum_hw attn[hw]*v  (head GEMV eliminated).
__global__ __launch_bounds__(256, 2) void moments_mfma(
    const _Float16* __restrict__ WvA, const _Float16* __restrict__ xpH,
    const float* __restrict__ attn_p,
    float* __restrict__ S1, float* __restrict__ S2, float* __restrict__ S3) {
  int bid = blockIdx.x;
  int ob = (bid >> 3) & 15;
  int nd = ((bid >> 7) << 3) | (bid & 7);
  int t = threadIdx.x;
  int w = t >> 6, lane = t & 63;
  int wq = w >> 1, wh = w & 1;
  int rbase = ob * 8 + wq * 4;
  int jbase = wh * 7;
  int nj = 7 - wh;               // 7 for wh=0, 6 for wh=1
  __shared__ char ldsb[26624];   // 2 x 13312 B buffers: [j(13)][granule(64)][16B]
  __shared__ float attn_sh[HWP];
  const _Float16* xph = xpH + (size_t)nd * HWP * 512;
  if (t < HWP) attn_sh[t] = attn_p[((size_t)nd * 4 + (ob >> 2)) * HWP + t];

  f32x4 acc[4][7];
  #pragma unroll
  for (int f = 0; f < 4; ++f)
    #pragma unroll
    for (int j = 0; j < 7; ++j) acc[f][j] = (f32x4){0.f, 0.f, 0.f, 0.f};

  auto stage = [&](char* buf, int kk) {
    #pragma unroll
    for (int i = 0; i < 4; ++i) {
      if (i < 3 || t < 64) {
        int G = i * 256 + t;
        int j = G >> 6;
        int g = G & 63;              // == lane
        int hwl = g & 15, bb = g >> 4;
        const _Float16* src = xph + (size_t)(j * 16 + hwl) * 512 + kk * 32 + bb * 8;
        gload_lds16((const void*)src, (void*)(buf + G * 16));
      }
    }
  };

  stage(ldsb, 0);
  half8 ah[4], al_[4], nah[4], nal[4];
  #pragma unroll
  for (int f = 0; f < 4; ++f) {
    ah[f]  = *(const half8*)(WvA + ((size_t)0 * 128 + rbase + f) * 512 + lane * 8);
    al_[f] = *(const half8*)(WvA + ((size_t)1 * 128 + rbase + f) * 512 + lane * 8);
  }
  __syncthreads();

  int cur = 0;
  for (int kk = 0; kk < 16; ++kk) {
    if (kk < 15) {
      #pragma unroll
      for (int f = 0; f < 4; ++f) {
        nah[f] = *(const half8*)(WvA + ((size_t)((kk + 1) * 2 + 0) * 128 + rbase + f) * 512 + lane * 8);
        nal[f] = *(const half8*)(WvA + ((size_t)((kk + 1) * 2 + 1) * 128 + rbase + f) * 512 + lane * 8);
      }
      stage(ldsb + (cur ^ 1) * 13312, kk + 1);
    }
    const char* bp = ldsb + cur * 13312;
    #pragma unroll
    for (int j = 0; j < 7; ++j) {
      if (j < nj) {
        half8 bh = *(const half8*)(bp + (jbase + j) * 1024 + lane * 16);
        #pragma unroll
        for (int f = 0; f < 4; ++f) {
          acc[f][j] = MFMAH(ah[f], bh, acc[f][j]);
          acc[f][j] = MFMAH(al_[f], bh, acc[f][j]);
        }
      }
    }
    __syncthreads();
    cur ^= 1;
    #pragma unroll
    for (int f = 0; f < 4; ++f) { ah[f] = nah[f]; al_[f] = nal[f]; }
  }

  // epilogue: S1, S2, S3 (attn-weighted). C/D layout: hw-col = lane&15, oc-row = (lane>>4)*4+r
  float attw[7];
  #pragma unroll
  for (int j = 0; j < 7; ++j) attw[j] = attn_sh[(jbase + j) * 16 + (lane & 15)];
  float* red = (float*)ldsb;
  float q1[4][4], q2[4][4], q3[4][4];
  #pragma unroll
  for (int f = 0; f < 4; ++f) {
    #pragma unroll
    for (int r = 0; r < 4; ++r) {
      float u = 0.f, vsq = 0.f, ws = 0.f;
      #pragma unroll
      for (int j = 0; j < 7; ++j) {
        float v = acc[f][j][r];
        u += v;
        vsq = fmaf(v, v, vsq);
        ws = fmaf(v, attw[j], ws);
      }
      #pragma unroll
      for (int off = 8; off; off >>= 1) {
        u += __shfl_xor(u, off, 16);
        vsq += __shfl_xor(vsq, off, 16);
        ws += __shfl_xor(ws, off, 16);
      }
      q1[f][r] = u; q2[f][r] = vsq; q3[f][r] = ws;
    }
  }
  int rowq = lane >> 4;
  bool wr = (lane & 15) == 0;
  if (wh == 0 && wr) {
    #pragma unroll
    for (int f = 0; f < 4; ++f)
      #pragma unroll
      for (int r = 0; r < 4; ++r) {
        int idx = wq * 64 + f * 16 + rowq * 4 + r;
        red[idx] = q1[f][r];
        red[128 + idx] = q2[f][r];
        red[256 + idx] = q3[f][r];
      }
  }
  __syncthreads();
  if (wh == 1 && wr) {
    size_t base = (size_t)nd * OC + ob * 128 + wq * 64;
    #pragma unroll
    for (int f = 0; f < 4; ++f)
      #pragma unroll
      for (int r = 0; r < 4; ++r) {
        int idx = f * 16 + rowq * 4 + r;
        S1[base + idx] = red[wq * 64 + idx] + q1[f][r];
        S2[base + idx] = red[128 + wq * 64 + idx] + q2[f][r];
        S3[base + idx] = red[256 + wq * 64 + idx] + q3[f][r];
      }
  }
}

// ---------------- head: per (nd,oc) InstanceNorm + gelu + Wout reduce (no GEMV) ----------------
__global__ void head_final(const float* __restrict__ S1, const float* __restrict__ S2,
                           const float* __restrict__ S3,
                           const float* __restrict__ gamma, const float* __restrict__ beta,
                           const float* __restrict__ Wout, const float* __restrict__ bout,
                           float* __restrict__ outs) {
  int nd = blockIdx.x;
  int t = threadIdx.x;
  int w = t >> 6, lane = t & 63;
  __shared__ float redp[16];
  float po[4] = {0.f, 0.f, 0.f, 0.f};
  #pragma unroll
  for (int i = 0; i < 8; ++i) {
    int oc = i * 256 + t;
    float m1 = S1[(size_t)nd * OC + oc] * INV196;
    float m2 = S2[(size_t)nd * OC + oc] * INV196;
    float var = m2 - m1 * m1;
    float rs = rsqrtf(var + 1e-5f);
    float xh = (S3[(size_t)nd * OC + oc] - m1) * rs * gamma[oc] + beta[oc];
    float ge = 0.5f * xh * (1.0f + erff(xh * 0.70710678118654752f));
    po[i >> 1] = fmaf(ge, Wout[oc], po[i >> 1]);
  }
  #pragma unroll
  for (int off = 32; off; off >>= 1) {
    #pragma unroll
    for (int o = 0; o < 4; ++o) po[o] += __shfl_down(po[o], off, 64);
  }
  if (lane == 0) {
    #pragma unroll
    for (int o = 0; o < 4; ++o) redp[w * 4 + o] = po[o];
  }
  __syncthreads();
  if (t < 4) {
    int o = t;
    float s = redp[o] + redp[4 + o] + redp[8 + o] + redp[12 + o] + bout[o];
    int n = nd >> 5, d = nd & 31;
    outs[o * 64 + n * 32 + d] = s;
  }
}

}  // namespace

extern "C" void kernel_launch(void* const* d_in, const int* in_sizes, int n_in,
                              void* d_out, int out_size, void* d_ws, size_t ws_size,
                              hipStream_t stream) {
  const float* x     = (const float*)d_in[0];
  const float* Wq    = (const float*)d_in[1];
  const float* Wk    = (const float*)d_in[2];
  const float* Wv    = (const float*)d_in[3];
  const float* gamma = (const float*)d_in[4];
  const float* beta  = (const float*)d_in[5];
  const float* Wout  = (const float*)d_in[6];
  const float* bout  = (const float*)d_in[7];
  float* out      = (float*)d_out;
  float* attn_out = out;            // (N,4,D,196) = 50176 floats
  float* outs     = out + 50176;    // (4,N,1,D)   = 256 floats

  float* ws = (float*)d_ws;
  _Float16*  WvA   = (_Float16*)ws;                     // 2097152 f16  -> [0, 1048576) floats
  _Float16*  xpH   = (_Float16*)(ws + 1048576);         // 7340032 f16
  _Float16*  xpL   = (_Float16*)(ws + 4718592);         // 7340032 f16
  float*     xm    = ws + 8388608;                      // 32768
  float*     dotb  = ws + 8421376;                      // 64*4*224 = 57344
  float*     attnp = ws + 8478720;                      // 57344
  float*     S1    = ws + 8536064;                      // 131072
  float*     S2    = ws + 8667136;                      // 131072
  float*     S3    = ws + 8798208;                      // 131072

  fat_prep<<<4608, 256, 0, stream>>>(x, Wv, WvA, xpH, xpL, xm);
  attn_dots<<<256, 256, 0, stream>>>(Wq, Wk, xm, xpH, xpL, dotb);
  attn_soft<<<256, 256, 0, stream>>>(dotb, attn_out, attnp);
  moments_mfma<<<1024, 256, 0, stream>>>(WvA, xpH, attnp, S1, S2, S3);
  head_final<<<64, 256, 0, stream>>>(S1, S2, S3, gamma, beta, Wout, bout, outs);
}

// Round 13
// 90.540 us; speedup vs baseline: 1.4300x; 1.0559x over previous
//
#include <hip/hip_runtime.h>
#include <math.h>

namespace {

constexpr int HW  = 196;
constexpr int HWP = 224;
constexpr int OC  = 2048;
constexpr float TEMP   = 0.35355339059327373f;  // 1/sqrt(KEY_DIM)
constexpr float INV196 = 1.0f / 196.0f;

typedef __attribute__((ext_vector_type(8))) _Float16 half8;
typedef __attribute__((ext_vector_type(4))) float f32x4;

__device__ __forceinline__ void gload_lds16(const void* g, void* l) {
  __builtin_amdgcn_global_load_lds(
      (const __attribute__((address_space(1))) void*)g,
      (__attribute__((address_space(3))) void*)l, 16, 0, 0);
}

#define MFMAH(a, b, c) __builtin_amdgcn_mfma_f32_16x16x32_f16((a), (b), (c), 0, 0, 0)

// ================= K1: WvA prep (512 blocks) || pool (4096 blocks, XCD-affine) =================
__global__ __launch_bounds__(256) void fat_prep(
    const float* __restrict__ x, const float* __restrict__ Wv,
    _Float16* __restrict__ WvA,
    _Float16* __restrict__ xpH, float* __restrict__ xm) {
  __shared__ float tl[8][264];
  int bid = blockIdx.x;
  int t = threadIdx.x;
  if (bid < 512) {
    // ---- WvA f16 hi/lo fragments ----
    int kk = bid >> 5;
    int rq = bid & 31;
    int w = t >> 6, lane = t & 63;
    int r = rq * 4 + w;
    int oc = r * 16 + (lane & 15);
    int c0 = kk * 32 + (lane >> 4) * 8;
    const float* src = Wv + (size_t)oc * 512 + c0;
    float4 v0 = *(const float4*)src;
    float4 v1 = *(const float4*)(src + 4);
    float vals[8] = {v0.x, v0.y, v0.z, v0.w, v1.x, v1.y, v1.z, v1.w};
    half8 hi, lo;
    #pragma unroll
    for (int e = 0; e < 8; ++e) {
      _Float16 h = (_Float16)vals[e];
      hi[e] = h;
      lo[e] = (_Float16)(vals[e] - (float)h);
    }
    *(half8*)(WvA + ((size_t)(kk * 2 + 0) * 128 + r) * 512 + lane * 8) = hi;
    *(half8*)(WvA + ((size_t)(kk * 2 + 1) * 128 + r) * 512 + lane * 8) = lo;
  } else {
    // ---- pool: avgpool3x3 + spatial mean -> f16 xp hi only, [nd][hw][c] ----
    int pb = bid - 512;
    int nd = (((pb >> 9) & 7) << 3) | (pb & 7);   // XCD-affine
    int cg = (pb >> 3) & 63;
    int n = nd >> 5, d = nd & 31;
    int c0 = cg * 8;
    int cl = t >> 5, s = t & 31;
    const float* xr = x + (((size_t)(n * 512 + c0 + cl)) * 32 + d) * 256;
    float4 va = *(const float4*)(xr + s * 8);
    float4 vb = *(const float4*)(xr + s * 8 + 4);
    *(float4*)&tl[cl][s * 8] = va;
    *(float4*)&tl[cl][s * 8 + 4] = vb;
    float rs = va.x + va.y + va.z + va.w + vb.x + vb.y + vb.z + vb.w;
    #pragma unroll
    for (int off = 16; off; off >>= 1) rs += __shfl_xor(rs, off, 32);
    if (s == 0) xm[nd * 512 + c0 + cl] = rs * (1.0f / 256.0f);
    __syncthreads();
    if (t < HWP) {
      int hw = t;
      half8 hi;
      if (hw < HW) {
        int y = hw / 14, xx = hw - y * 14;
        #pragma unroll
        for (int c = 0; c < 8; ++c) {
          const float* q = &tl[c][y * 16 + xx];
          float val = (q[0] + q[1] + q[2] + q[16] + q[17] + q[18] +
                       q[32] + q[33] + q[34]) * (1.0f / 9.0f);
          hi[c] = (_Float16)val;
        }
      } else {
        #pragma unroll
        for (int c = 0; c < 8; ++c) hi[c] = (_Float16)0.f;
      }
      *(half8*)(xpH + ((size_t)nd * HWP + hw) * 512 + c0) = hi;
    }
  }
}

// ---------------- attn dots: dot[nd][o][hw] = qw[o] . xp_hi[hw]  (4 lanes per hw) ----------------
__global__ __launch_bounds__(256) void attn_dots(
    const float* __restrict__ Wq, const float* __restrict__ Wk,
    const float* __restrict__ xm,
    const _Float16* __restrict__ xpH, float* __restrict__ dotb) {
  int b = blockIdx.x;
  int nd = b >> 2, ch = b & 3;
  int t = threadIdx.x;
  __shared__ float xs[512];
  __shared__ float qsA[32];
  __shared__ float qw[2048];
  xs[t] = xm[nd * 512 + t];
  xs[t + 256] = xm[nd * 512 + t + 256];
  __syncthreads();
  {
    int k = t >> 3, j = t & 7;
    float p = 0.f;
    #pragma unroll 8
    for (int c = j; c < 512; c += 8) p = fmaf(Wq[k * 512 + c], xs[c], p);
    p += __shfl_xor(p, 4, 8);
    p += __shfl_xor(p, 2, 8);
    p += __shfl_xor(p, 1, 8);
    if (j == 0) qsA[k] = p;
  }
  __syncthreads();
  {
    int o = t >> 6;
    int c0 = (t & 63) * 8;
    float q[8];
    #pragma unroll
    for (int kd = 0; kd < 8; ++kd) q[kd] = qsA[o * 8 + kd];
    #pragma unroll
    for (int e = 0; e < 8; ++e) {
      float a = 0.f;
      #pragma unroll
      for (int kd = 0; kd < 8; ++kd)
        a = fmaf(q[kd], Wk[(size_t)(o * 8 + kd) * 512 + c0 + e], a);
      qw[o * 512 + c0 + e] = a;
    }
  }
  __syncthreads();
  if (t < 224) {
    int hwl = t >> 2, q = t & 3;
    int hw = ch * 56 + hwl;
    const _Float16* rh = xpH + ((size_t)nd * HWP + hw) * 512;
    float d0 = 0.f, d1 = 0.f, d2 = 0.f, d3 = 0.f;
    #pragma unroll
    for (int k = 0; k < 16; ++k) {
      int cb = q * 8 + k * 32;           // interleaved c-blocks: conflict-free qw banks
      half8 h = *(const half8*)(rh + cb);
      #pragma unroll
      for (int e = 0; e < 8; ++e) {
        float xv = (float)h[e];
        d0 = fmaf(qw[cb + e], xv, d0);
        d1 = fmaf(qw[512 + cb + e], xv, d1);
        d2 = fmaf(qw[1024 + cb + e], xv, d2);
        d3 = fmaf(qw[1536 + cb + e], xv, d3);
      }
    }
    d0 += __shfl_xor(d0, 1, 4); d0 += __shfl_xor(d0, 2, 4);
    d1 += __shfl_xor(d1, 1, 4); d1 += __shfl_xor(d1, 2, 4);
    d2 += __shfl_xor(d2, 1, 4); d2 += __shfl_xor(d2, 2, 4);
    d3 += __shfl_xor(d3, 1, 4); d3 += __shfl_xor(d3, 2, 4);
    float r = (q == 0) ? d0 : (q == 1) ? d1 : (q == 2) ? d2 : d3;
    dotb[((size_t)nd * 4 + q) * HWP + hw] = r * TEMP;
  }
}

// ---------------- moments + inline softmax + attention-weighted sum (2-product f16 MFMA) ----------
// grid 1024: nd-XCD-affine; block tile 128 oc x 208 hw; o = ob>>2.
// Prologue: softmax of dotb row (exact div) -> attn_sh; ob&3==0 blocks write attn_out.
// Epilogue: S1 = sum_hw v, S2 = sum_hw v^2, S3 = sum_hw attn*v.
__global__ __launch_bounds__(256, 2) void moments_mfma(
    const _Float16* __restrict__ WvA, const _Float16* __restrict__ xpH,
    const float* __restrict__ dotb, float* __restrict__ attn_out,
    float* __restrict__ S1, float* __restrict__ S2, float* __restrict__ S3) {
  int bid = blockIdx.x;
  int ob = (bid >> 3) & 15;
  int nd = ((bid >> 7) << 3) | (bid & 7);
  int o = ob >> 2;
  int t = threadIdx.x;
  int w = t >> 6, lane = t & 63;
  int wq = w >> 1, wh = w & 1;
  int rbase = ob * 8 + wq * 4;
  int jbase = wh * 7;
  int nj = 7 - wh;               // 7 for wh=0, 6 for wh=1
  __shared__ char ldsb[26624];   // 2 x 13312 B buffers: [j(13)][granule(64)][16B]
  __shared__ float attn_sh[HWP];
  __shared__ float redm[4];
  __shared__ float reds[4];
  const _Float16* xph = xpH + (size_t)nd * HWP * 512;

  // issue dot load early (latency overlaps staging below)
  float vdot = (t < HW) ? dotb[((size_t)nd * 4 + o) * HWP + t] : -3.0e38f;

  f32x4 acc[4][7];
  #pragma unroll
  for (int f = 0; f < 4; ++f)
    #pragma unroll
    for (int j = 0; j < 7; ++j) acc[f][j] = (f32x4){0.f, 0.f, 0.f, 0.f};

  auto stage = [&](char* buf, int kk) {
    #pragma unroll
    for (int i = 0; i < 4; ++i) {
      if (i < 3 || t < 64) {
        int G = i * 256 + t;
        int j = G >> 6;
        int g = G & 63;              // == lane
        int hwl = g & 15, bb = g >> 4;
        const _Float16* src = xph + (size_t)(j * 16 + hwl) * 512 + kk * 32 + bb * 8;
        gload_lds16((const void*)src, (void*)(buf + G * 16));
      }
    }
  };

  stage(ldsb, 0);
  half8 ah[4], al_[4], nah[4], nal[4];
  #pragma unroll
  for (int f = 0; f < 4; ++f) {
    ah[f]  = *(const half8*)(WvA + ((size_t)0 * 128 + rbase + f) * 512 + lane * 8);
    al_[f] = *(const half8*)(WvA + ((size_t)1 * 128 + rbase + f) * 512 + lane * 8);
  }

  // ---- inline softmax (exact division; pad lanes contribute e = 0) ----
  {
    float m = vdot;
    #pragma unroll
    for (int off = 32; off; off >>= 1) m = fmaxf(m, __shfl_xor(m, off, 64));
    if (lane == 0) redm[w] = m;
    __syncthreads();
    float bm = fmaxf(fmaxf(redm[0], redm[1]), fmaxf(redm[2], redm[3]));
    float e = (t < HW) ? expf(vdot - bm) : 0.f;
    float s = e;
    #pragma unroll
    for (int off = 32; off; off >>= 1) s += __shfl_xor(s, off, 64);
    if (lane == 0) reds[w] = s;
    __syncthreads();
    float bs = reds[0] + reds[1] + reds[2] + reds[3];
    float a = (t < HW) ? (e / bs) : 0.f;
    if (t < HWP) attn_sh[t] = a;
    if ((ob & 3) == 0 && t < HW) {
      int n = nd >> 5, d = nd & 31;
      attn_out[(((size_t)n * 4 + o) * 32 + d) * HW + t] = a;
    }
  }
  __syncthreads();   // stage-0 drained; attn_sh visible

  int cur = 0;
  for (int kk = 0; kk < 16; ++kk) {
    if (kk < 15) {
      #pragma unroll
      for (int f = 0; f < 4; ++f) {
        nah[f] = *(const half8*)(WvA + ((size_t)((kk + 1) * 2 + 0) * 128 + rbase + f) * 512 + lane * 8);
        nal[f] = *(const half8*)(WvA + ((size_t)((kk + 1) * 2 + 1) * 128 + rbase + f) * 512 + lane * 8);
      }
      stage(ldsb + (cur ^ 1) * 13312, kk + 1);
    }
    const char* bp = ldsb + cur * 13312;
    #pragma unroll
    for (int j = 0; j < 7; ++j) {
      if (j < nj) {
        half8 bh = *(const half8*)(bp + (jbase + j) * 1024 + lane * 16);
        #pragma unroll
        for (int f = 0; f < 4; ++f) {
          acc[f][j] = MFMAH(ah[f], bh, acc[f][j]);
          acc[f][j] = MFMAH(al_[f], bh, acc[f][j]);
        }
      }
    }
    __syncthreads();
    cur ^= 1;
    #pragma unroll
    for (int f = 0; f < 4; ++f) { ah[f] = nah[f]; al_[f] = nal[f]; }
  }

  // epilogue: S1, S2, S3. C/D layout: hw-col = lane&15, oc-row = (lane>>4)*4+r
  float attw[7];
  #pragma unroll
  for (int j = 0; j < 7; ++j) attw[j] = attn_sh[(jbase + j) * 16 + (lane & 15)];
  float* red = (float*)ldsb;
  float q1[4][4], q2[4][4], q3[4][4];
  #pragma unroll
  for (int f = 0; f < 4; ++f) {
    #pragma unroll
    for (int r = 0; r < 4; ++r) {
      float u = 0.f, vsq = 0.f, wsum = 0.f;
      #pragma unroll
      for (int j = 0; j < 7; ++j) {
        float v = acc[f][j][r];
        u += v;
        vsq = fmaf(v, v, vsq);
        wsum = fmaf(v, attw[j], wsum);
      }
      #pragma unroll
      for (int off = 8; off; off >>= 1) {
        u += __shfl_xor(u, off, 16);
        vsq += __shfl_xor(vsq, off, 16);
        wsum += __shfl_xor(wsum, off, 16);
      }
      q1[f][r] = u; q2[f][r] = vsq; q3[f][r] = wsum;
    }
  }
  int rowq = lane >> 4;
  bool wr = (lane & 15) == 0;
  if (wh == 0 && wr) {
    #pragma unroll
    for (int f = 0; f < 4; ++f)
      #pragma unroll
      for (int r = 0; r < 4; ++r) {
        int idx = wq * 64 + f * 16 + rowq * 4 + r;
        red[idx] = q1[f][r];
        red[128 + idx] = q2[f][r];
        red[256 + idx] = q3[f][r];
      }
  }
  __syncthreads();
  if (wh == 1 && wr) {
    size_t base = (size_t)nd * OC + ob * 128 + wq * 64;
    #pragma unroll
    for (int f = 0; f < 4; ++f)
      #pragma unroll
      for (int r = 0; r < 4; ++r) {
        int idx = f * 16 + rowq * 4 + r;
        S1[base + idx] = red[wq * 64 + idx] + q1[f][r];
        S2[base + idx] = red[128 + wq * 64 + idx] + q2[f][r];
        S3[base + idx] = red[256 + wq * 64 + idx] + q3[f][r];
      }
  }
}

// ---------------- head: per (nd,oc) InstanceNorm + gelu + Wout reduce ----------------
__global__ void head_final(const float* __restrict__ S1, const float* __restrict__ S2,
                           const float* __restrict__ S3,
                           const float* __restrict__ gamma, const float* __restrict__ beta,
                           const float* __restrict__ Wout, const float* __restrict__ bout,
                           float* __restrict__ outs) {
  int nd = blockIdx.x;
  int t = threadIdx.x;
  int w = t >> 6, lane = t & 63;
  __shared__ float redp[16];
  float po[4] = {0.f, 0.f, 0.f, 0.f};
  #pragma unroll
  for (int i = 0; i < 8; ++i) {
    int oc = i * 256 + t;
    float m1 = S1[(size_t)nd * OC + oc] * INV196;
    float m2 = S2[(size_t)nd * OC + oc] * INV196;
    float var = m2 - m1 * m1;
    float rs = rsqrtf(var + 1e-5f);
    float xh = (S3[(size_t)nd * OC + oc] - m1) * rs * gamma[oc] + beta[oc];
    float ge = 0.5f * xh * (1.0f + erff(xh * 0.70710678118654752f));
    po[i >> 1] = fmaf(ge, Wout[oc], po[i >> 1]);
  }
  #pragma unroll
  for (int off = 32; off; off >>= 1) {
    #pragma unroll
    for (int o = 0; o < 4; ++o) po[o] += __shfl_down(po[o], off, 64);
  }
  if (lane == 0) {
    #pragma unroll
    for (int o = 0; o < 4; ++o) redp[w * 4 + o] = po[o];
  }
  __syncthreads();
  if (t < 4) {
    int o = t;
    float s = redp[o] + redp[4 + o] + redp[8 + o] + redp[12 + o] + bout[o];
    int n = nd >> 5, d = nd & 31;
    outs[o * 64 + n * 32 + d] = s;
  }
}

}  // namespace

extern "C" void kernel_launch(void* const* d_in, const int* in_sizes, int n_in,
                              void* d_out, int out_size, void* d_ws, size_t ws_size,
                              hipStream_t stream) {
  const float* x     = (const float*)d_in[0];
  const float* Wq    = (const float*)d_in[1];
  const float* Wk    = (const float*)d_in[2];
  const float* Wv    = (const float*)d_in[3];
  const float* gamma = (const float*)d_in[4];
  const float* beta  = (const float*)d_in[5];
  const float* Wout  = (const float*)d_in[6];
  const float* bout  = (const float*)d_in[7];
  float* out      = (float*)d_out;
  float* attn_out = out;            // (N,4,D,196) = 50176 floats
  float* outs     = out + 50176;    // (4,N,1,D)   = 256 floats

  float* ws = (float*)d_ws;
  _Float16*  WvA  = (_Float16*)ws;                      // 2097152 f16 -> [0, 1048576) floats
  _Float16*  xpH  = (_Float16*)(ws + 1048576);          // 7340032 f16 -> 3670016 floats
  float*     xm   = ws + 4718592;                       // 32768
  float*     dotb = ws + 4751360;                       // 57344
  float*     S1   = ws + 4808704;                       // 131072
  float*     S2   = ws + 4939776;                       // 131072
  float*     S3   = ws + 5070848;                       // 131072

  fat_prep<<<4608, 256, 0, stream>>>(x, Wv, WvA, xpH, xm);
  attn_dots<<<256, 256, 0, stream>>>(Wq, Wk, xm, xpH, dotb);
  moments_mfma<<<1024, 256, 0, stream>>>(WvA, xpH, dotb, attn_out, S1, S2, S3);
  head_final<<<64, 256, 0, stream>>>(S1, S2, S3, gamma, beta, Wout, bout, outs);
}

// Round 14
// 88.953 us; speedup vs baseline: 1.4555x; 1.0178x over previous
//
#include <hip/hip_runtime.h>
#include <math.h>

namespace {

constexpr int HW  = 196;
constexpr int HWP = 224;
constexpr int OC  = 2048;
constexpr float TEMP   = 0.35355339059327373f;  // 1/sqrt(KEY_DIM)
constexpr float INV196 = 1.0f / 196.0f;

typedef __attribute__((ext_vector_type(8))) _Float16 half8;
typedef __attribute__((ext_vector_type(4))) float f32x4;

__device__ __forceinline__ void gload_lds16(const void* g, void* l) {
  __builtin_amdgcn_global_load_lds(
      (const __attribute__((address_space(1))) void*)g,
      (__attribute__((address_space(3))) void*)l, 16, 0, 0);
}

#define MFMAH(a, b, c) __builtin_amdgcn_mfma_f32_16x16x32_f16((a), (b), (c), 0, 0, 0)

// ================= K1: WvA prep (512 blocks) || pool (4096 blocks, XCD-affine) =================
__global__ __launch_bounds__(256) void fat_prep(
    const float* __restrict__ x, const float* __restrict__ Wv,
    _Float16* __restrict__ WvA,
    _Float16* __restrict__ xpH, float* __restrict__ xm) {
  __shared__ float tl[8][264];
  int bid = blockIdx.x;
  int t = threadIdx.x;
  if (bid < 512) {
    // ---- WvA f16 hi/lo fragments ----
    int kk = bid >> 5;
    int rq = bid & 31;
    int w = t >> 6, lane = t & 63;
    int r = rq * 4 + w;
    int oc = r * 16 + (lane & 15);
    int c0 = kk * 32 + (lane >> 4) * 8;
    const float* src = Wv + (size_t)oc * 512 + c0;
    float4 v0 = *(const float4*)src;
    float4 v1 = *(const float4*)(src + 4);
    float vals[8] = {v0.x, v0.y, v0.z, v0.w, v1.x, v1.y, v1.z, v1.w};
    half8 hi, lo;
    #pragma unroll
    for (int e = 0; e < 8; ++e) {
      _Float16 h = (_Float16)vals[e];
      hi[e] = h;
      lo[e] = (_Float16)(vals[e] - (float)h);
    }
    *(half8*)(WvA + ((size_t)(kk * 2 + 0) * 128 + r) * 512 + lane * 8) = hi;
    *(half8*)(WvA + ((size_t)(kk * 2 + 1) * 128 + r) * 512 + lane * 8) = lo;
  } else {
    // ---- pool: avgpool3x3 + spatial mean -> f16 xp hi only, [nd][hw][c] ----
    int pb = bid - 512;
    int nd = (((pb >> 9) & 7) << 3) | (pb & 7);   // XCD-affine
    int cg = (pb >> 3) & 63;
    int n = nd >> 5, d = nd & 31;
    int c0 = cg * 8;
    int cl = t >> 5, s = t & 31;
    const float* xr = x + (((size_t)(n * 512 + c0 + cl)) * 32 + d) * 256;
    float4 va = *(const float4*)(xr + s * 8);
    float4 vb = *(const float4*)(xr + s * 8 + 4);
    *(float4*)&tl[cl][s * 8] = va;
    *(float4*)&tl[cl][s * 8 + 4] = vb;
    float rs = va.x + va.y + va.z + va.w + vb.x + vb.y + vb.z + vb.w;
    #pragma unroll
    for (int off = 16; off; off >>= 1) rs += __shfl_xor(rs, off, 32);
    if (s == 0) xm[nd * 512 + c0 + cl] = rs * (1.0f / 256.0f);
    __syncthreads();
    if (t < HWP) {
      int hw = t;
      half8 hi;
      if (hw < HW) {
        int y = hw / 14, xx = hw - y * 14;
        #pragma unroll
        for (int c = 0; c < 8; ++c) {
          const float* q = &tl[c][y * 16 + xx];
          float val = (q[0] + q[1] + q[2] + q[16] + q[17] + q[18] +
                       q[32] + q[33] + q[34]) * (1.0f / 9.0f);
          hi[c] = (_Float16)val;
        }
      } else {
        #pragma unroll
        for (int c = 0; c < 8; ++c) hi[c] = (_Float16)0.f;
      }
      *(half8*)(xpH + ((size_t)nd * HWP + hw) * 512 + c0) = hi;
    }
  }
}

// ---------------- attn dots: dot[nd][o][hw] = qw[o] . xp_hi[hw]  (4 lanes per hw) ----------------
__global__ __launch_bounds__(256) void attn_dots(
    const float* __restrict__ Wq, const float* __restrict__ Wk,
    const float* __restrict__ xm,
    const _Float16* __restrict__ xpH, float* __restrict__ dotb) {
  int b = blockIdx.x;
  int nd = b >> 2, ch = b & 3;
  int t = threadIdx.x;
  __shared__ float xs[512];
  __shared__ float qsA[32];
  __shared__ float qw[2048];
  xs[t] = xm[nd * 512 + t];
  xs[t + 256] = xm[nd * 512 + t + 256];
  __syncthreads();
  {
    int k = t >> 3, j = t & 7;
    float p = 0.f;
    #pragma unroll 8
    for (int c = j; c < 512; c += 8) p = fmaf(Wq[k * 512 + c], xs[c], p);
    p += __shfl_xor(p, 4, 8);
    p += __shfl_xor(p, 2, 8);
    p += __shfl_xor(p, 1, 8);
    if (j == 0) qsA[k] = p;
  }
  __syncthreads();
  {
    int o = t >> 6;
    int c0 = (t & 63) * 8;
    float q[8];
    #pragma unroll
    for (int kd = 0; kd < 8; ++kd) q[kd] = qsA[o * 8 + kd];
    #pragma unroll
    for (int e = 0; e < 8; ++e) {
      float a = 0.f;
      #pragma unroll
      for (int kd = 0; kd < 8; ++kd)
        a = fmaf(q[kd], Wk[(size_t)(o * 8 + kd) * 512 + c0 + e], a);
      qw[o * 512 + c0 + e] = a;
    }
  }
  __syncthreads();
  if (t < 224) {
    int hwl = t >> 2, q = t & 3;
    int hw = ch * 56 + hwl;
    const _Float16* rh = xpH + ((size_t)nd * HWP + hw) * 512;
    float d0 = 0.f, d1 = 0.f, d2 = 0.f, d3 = 0.f;
    #pragma unroll
    for (int k = 0; k < 16; ++k) {
      int cb = q * 8 + k * 32;           // interleaved c-blocks: conflict-free qw banks
      half8 h = *(const half8*)(rh + cb);
      #pragma unroll
      for (int e = 0; e < 8; ++e) {
        float xv = (float)h[e];
        d0 = fmaf(qw[cb + e], xv, d0);
        d1 = fmaf(qw[512 + cb + e], xv, d1);
        d2 = fmaf(qw[1024 + cb + e], xv, d2);
        d3 = fmaf(qw[1536 + cb + e], xv, d3);
      }
    }
    d0 += __shfl_xor(d0, 1, 4); d0 += __shfl_xor(d0, 2, 4);
    d1 += __shfl_xor(d1, 1, 4); d1 += __shfl_xor(d1, 2, 4);
    d2 += __shfl_xor(d2, 1, 4); d2 += __shfl_xor(d2, 2, 4);
    d3 += __shfl_xor(d3, 1, 4); d3 += __shfl_xor(d3, 2, 4);
    float r = (q == 0) ? d0 : (q == 1) ? d1 : (q == 2) ? d2 : d3;
    dotb[((size_t)nd * 4 + q) * HWP + hw] = r * TEMP;
  }
}

// ---------------- moments + inline softmax + attention-weighted sum (2-product f16 MFMA) ----------
// 3-deep counted-vmcnt pipeline. Per-wave vmem ledger per iteration (post-barrier-B region):
// 8 A-loads + 4 B-stages = 12. buf[kk] staged 2 iterations ago => s_waitcnt vmcnt(12) before
// barrier-A guarantees it landed (vmcnt(8) for kk=15: no stage in iter 14's region).
// Every wave issues exactly 4 stage instructions (round 3 via lane<16 per wave).
__global__ __launch_bounds__(256, 2) void moments_mfma(
    const _Float16* __restrict__ WvA, const _Float16* __restrict__ xpH,
    const float* __restrict__ dotb, float* __restrict__ attn_out,
    float* __restrict__ S1, float* __restrict__ S2, float* __restrict__ S3) {
  int bid = blockIdx.x;
  int ob = (bid >> 3) & 15;
  int nd = ((bid >> 7) << 3) | (bid & 7);
  int o = ob >> 2;
  int t = threadIdx.x;
  int w = t >> 6, lane = t & 63;
  int wq = w >> 1, wh = w & 1;
  int rbase = ob * 8 + wq * 4;
  int jbase = wh * 7;
  int nj = 7 - wh;               // 7 for wh=0, 6 for wh=1
  __shared__ char ldsb[39936];   // 3 x 13312 B buffers: [j(13)][granule(64)][16B]
  __shared__ float attn_sh[HWP];
  __shared__ float redm[4];
  __shared__ float reds[4];
  const _Float16* xph = xpH + (size_t)nd * HWP * 512;

  // 1 vmem: dot row load (latency hides under staging)
  float vdot = (t < HW) ? dotb[((size_t)nd * 4 + o) * HWP + t] : -3.0e38f;

  f32x4 acc[4][7];
  #pragma unroll
  for (int f = 0; f < 4; ++f)
    #pragma unroll
    for (int j = 0; j < 7; ++j) acc[f][j] = (f32x4){0.f, 0.f, 0.f, 0.f};

  // stage one 13312B B-tile: every wave issues exactly 4 gload_lds instructions
  auto stage = [&](char* buf, int kk) {
    #pragma unroll
    for (int i = 0; i < 3; ++i) {
      int G = i * 256 + t;
      int j = G >> 6, g = G & 63;
      int hwl = g & 15, bb = g >> 4;
      const _Float16* src = xph + (size_t)(j * 16 + hwl) * 512 + kk * 32 + bb * 8;
      gload_lds16((const void*)src, (void*)(buf + G * 16));
    }
    if (lane < 16) {                       // round 3: 16 granules per wave
      int G = 768 + w * 16 + lane;
      int g = G & 63;
      int hwl = g & 15, bb = g >> 4;
      const _Float16* src = xph + (size_t)(12 * 16 + hwl) * 512 + kk * 32 + bb * 8;
      gload_lds16((const void*)src, (void*)(buf + G * 16));
    }
  };

  stage(ldsb, 0);                          // buf0: 4 vmem/wave
  __builtin_amdgcn_sched_barrier(0);       // pin: ledger ops below stay below buf0's stages
  stage(ldsb + 13312, 1);                  // buf1: 4
  half8 ah[4], al_[4];
  #pragma unroll
  for (int f = 0; f < 4; ++f) {            // A(0): 8
    ah[f]  = *(const half8*)(WvA + ((size_t)0 * 128 + rbase + f) * 512 + lane * 8);
    al_[f] = *(const half8*)(WvA + ((size_t)1 * 128 + rbase + f) * 512 + lane * 8);
  }

  // ---- inline softmax (exact division); lgkm-only barriers keep stage loads in flight ----
  {
    float m = vdot;
    #pragma unroll
    for (int off = 32; off; off >>= 1) m = fmaxf(m, __shfl_xor(m, off, 64));
    if (lane == 0) redm[w] = m;
    asm volatile("s_waitcnt lgkmcnt(0)" ::: "memory");
    __builtin_amdgcn_s_barrier();
    float bm = fmaxf(fmaxf(redm[0], redm[1]), fmaxf(redm[2], redm[3]));
    float e = (t < HW) ? expf(vdot - bm) : 0.f;
    float s = e;
    #pragma unroll
    for (int off = 32; off; off >>= 1) s += __shfl_xor(s, off, 64);
    if (lane == 0) reds[w] = s;
    asm volatile("s_waitcnt lgkmcnt(0)" ::: "memory");
    __builtin_amdgcn_s_barrier();
    float bs = reds[0] + reds[1] + reds[2] + reds[3];
    float a = (t < HW) ? (e / bs) : 0.f;
    if (t < HWP) attn_sh[t] = a;
    if ((ob & 3) == 0 && t < HW) {
      int n = nd >> 5, d = nd & 31;
      attn_out[(((size_t)n * 4 + o) * 32 + d) * HW + t] = a;   // +1 vmem store (block-uniform)
    }
  }

  // ---- main pipelined loop: barrier-A (counted vmcnt) / MFMA / barrier-B (lgkm) / prefetch ----
  #pragma unroll
  for (int kk = 0; kk < 16; ++kk) {
    if (kk == 15) {
      asm volatile("s_waitcnt vmcnt(8) lgkmcnt(0)" ::: "memory");
    } else {
      asm volatile("s_waitcnt vmcnt(12) lgkmcnt(0)" ::: "memory");
    }
    __builtin_amdgcn_s_barrier();
    __builtin_amdgcn_sched_barrier(0);
    const char* bp = ldsb + (kk % 3) * 13312;
    #pragma unroll
    for (int j = 0; j < 7; ++j) {
      if (j < nj) {
        half8 bh = *(const half8*)(bp + (jbase + j) * 1024 + lane * 16);
        #pragma unroll
        for (int f = 0; f < 4; ++f) {
          acc[f][j] = MFMAH(ah[f], bh, acc[f][j]);
          acc[f][j] = MFMAH(al_[f], bh, acc[f][j]);
        }
      }
    }
    __builtin_amdgcn_sched_barrier(0);
    asm volatile("s_waitcnt lgkmcnt(0)" ::: "memory");
    __builtin_amdgcn_s_barrier();
    if (kk < 15) {
      #pragma unroll
      for (int f = 0; f < 4; ++f) {        // A(kk+1): 8 vmem
        ah[f]  = *(const half8*)(WvA + ((size_t)((kk + 1) * 2 + 0) * 128 + rbase + f) * 512 + lane * 8);
        al_[f] = *(const half8*)(WvA + ((size_t)((kk + 1) * 2 + 1) * 128 + rbase + f) * 512 + lane * 8);
      }
    }
    if (kk < 14) stage(ldsb + ((kk + 2) % 3) * 13312, kk + 2);   // 4 vmem
  }

  // epilogue: S1, S2, S3. C/D layout: hw-col = lane&15, oc-row = (lane>>4)*4+r
  float attw[7];
  #pragma unroll
  for (int j = 0; j < 7; ++j) attw[j] = attn_sh[(jbase + j) * 16 + (lane & 15)];
  float* red = (float*)ldsb;    // overlay: all B-buffers dead after final barrier-B
  float q1[4][4], q2[4][4], q3[4][4];
  #pragma unroll
  for (int f = 0; f < 4; ++f) {
    #pragma unroll
    for (int r = 0; r < 4; ++r) {
      float u = 0.f, vsq = 0.f, wsum = 0.f;
      #pragma unroll
      for (int j = 0; j < 7; ++j) {
        float v = acc[f][j][r];
        u += v;
        vsq = fmaf(v, v, vsq);
        wsum = fmaf(v, attw[j], wsum);
      }
      #pragma unroll
      for (int off = 8; off; off >>= 1) {
        u += __shfl_xor(u, off, 16);
        vsq += __shfl_xor(vsq, off, 16);
        wsum += __shfl_xor(wsum, off, 16);
      }
      q1[f][r] = u; q2[f][r] = vsq; q3[f][r] = wsum;
    }
  }
  int rowq = lane >> 4;
  bool wr = (lane & 15) == 0;
  if (wh == 0 && wr) {
    #pragma unroll
    for (int f = 0; f < 4; ++f)
      #pragma unroll
      for (int r = 0; r < 4; ++r) {
        int idx = wq * 64 + f * 16 + rowq * 4 + r;
        red[idx] = q1[f][r];
        red[128 + idx] = q2[f][r];
        red[256 + idx] = q3[f][r];
      }
  }
  __syncthreads();
  if (wh == 1 && wr) {
    size_t base = (size_t)nd * OC + ob * 128 + wq * 64;
    #pragma unroll
    for (int f = 0; f < 4; ++f)
      #pragma unroll
      for (int r = 0; r < 4; ++r) {
        int idx = f * 16 + rowq * 4 + r;
        S1[base + idx] = red[wq * 64 + idx] + q1[f][r];
        S2[base + idx] = red[128 + wq * 64 + idx] + q2[f][r];
        S3[base + idx] = red[256 + wq * 64 + idx] + q3[f][r];
      }
  }
}

// ---------------- head: per (nd,oc) InstanceNorm + gelu + Wout reduce ----------------
__global__ void head_final(const float* __restrict__ S1, const float* __restrict__ S2,
                           const float* __restrict__ S3,
                           const float* __restrict__ gamma, const float* __restrict__ beta,
                           const float* __restrict__ Wout, const float* __restrict__ bout,
                           float* __restrict__ outs) {
  int nd = blockIdx.x;
  int t = threadIdx.x;
  int w = t >> 6, lane = t & 63;
  __shared__ float redp[16];
  float po[4] = {0.f, 0.f, 0.f, 0.f};
  #pragma unroll
  for (int i = 0; i < 8; ++i) {
    int oc = i * 256 + t;
    float m1 = S1[(size_t)nd * OC + oc] * INV196;
    float m2 = S2[(size_t)nd * OC + oc] * INV196;
    float var = m2 - m1 * m1;
    float rs = rsqrtf(var + 1e-5f);
    float xh = (S3[(size_t)nd * OC + oc] - m1) * rs * gamma[oc] + beta[oc];
    float ge = 0.5f * xh * (1.0f + erff(xh * 0.70710678118654752f));
    po[i >> 1] = fmaf(ge, Wout[oc], po[i >> 1]);
  }
  #pragma unroll
  for (int off = 32; off; off >>= 1) {
    #pragma unroll
    for (int o = 0; o < 4; ++o) po[o] += __shfl_down(po[o], off, 64);
  }
  if (lane == 0) {
    #pragma unroll
    for (int o = 0; o < 4; ++o) redp[w * 4 + o] = po[o];
  }
  __syncthreads();
  if (t < 4) {
    int o = t;
    float s = redp[o] + redp[4 + o] + redp[8 + o] + redp[12 + o] + bout[o];
    int n = nd >> 5, d = nd & 31;
    outs[o * 64 + n * 32 + d] = s;
  }
}

}  // namespace

extern "C" void kernel_launch(void* const* d_in, const int* in_sizes, int n_in,
                              void* d_out, int out_size, void* d_ws, size_t ws_size,
                              hipStream_t stream) {
  const float* x     = (const float*)d_in[0];
  const float* Wq    = (const float*)d_in[1];
  const float* Wk    = (const float*)d_in[2];
  const float* Wv    = (const float*)d_in[3];
  const float* gamma = (const float*)d_in[4];
  const float* beta  = (const float*)d_in[5];
  const float* Wout  = (const float*)d_in[6];
  const float* bout  = (const float*)d_in[7];
  float* out      = (float*)d_out;
  float* attn_out = out;            // (N,4,D,196) = 50176 floats
  float* outs     = out + 50176;    // (4,N,1,D)   = 256 floats

  float* ws = (float*)d_ws;
  _Float16*  WvA  = (_Float16*)ws;                      // 2097152 f16 -> [0, 1048576) floats
  _Float16*  xpH  = (_Float16*)(ws + 1048576);          // 7340032 f16 -> 3670016 floats
  float*     xm   = ws + 4718592;                       // 32768
  float*     dotb = ws + 4751360;                       // 57344
  float*     S1   = ws + 4808704;                       // 131072
  float*     S2   = ws + 4939776;                       // 131072
  float*     S3   = ws + 5070848;                       // 131072

  fat_prep<<<4608, 256, 0, stream>>>(x, Wv, WvA, xpH, xm);
  attn_dots<<<256, 256, 0, stream>>>(Wq, Wk, xm, xpH, dotb);
  moments_mfma<<<1024, 256, 0, stream>>>(WvA, xpH, dotb, attn_out, S1, S2, S3);
  head_final<<<64, 256, 0, stream>>>(S1, S2, S3, gamma, beta, Wout, bout, outs);
}